// Round 6
// baseline (513.145 us; speedup 1.0000x reference)
//
#include <hip/hip_runtime.h>
#include <hip/hip_bf16.h>

#define N_NODES 50000
#define N_EDGES 1600000
#define HEADS 8
#define HDIM 16
#define D1 128   // HEADS*HDIM
#define NEG_SLOPE 0.2f
#define SCAN_BLKS 196  // ceil(50000/256)
#define RTILES 3125    // 50000/16

typedef short short8 __attribute__((ext_vector_type(8)));
typedef float f32x4 __attribute__((ext_vector_type(4)));
typedef _Float16 half2v __attribute__((ext_vector_type(2)));

// ---- dtype helpers (flag: 1 = buffers are fp32, 0 = bf16) ----
__device__ __forceinline__ float bf2f(ushort u) {
    union { unsigned u; float f; } x; x.u = ((unsigned)u) << 16; return x.f;
}
__device__ __forceinline__ ushort f2bf(float f) {
    union { float f; unsigned u; } x; x.f = f;
    unsigned r = x.u + 0x7FFF + ((x.u >> 16) & 1);   // RNE
    return (ushort)(r >> 16);
}
__device__ __forceinline__ float ldf(const void* p, size_t i, int isf32) {
    return isf32 ? ((const float*)p)[i] : bf2f(((const ushort*)p)[i]);
}
// split f into hi (truncated bf16) + lo (RNE bf16 of residual): ~2^-17 rel combined
__device__ __forceinline__ void splitbf(float f, ushort& hi, ushort& lo) {
    unsigned u = __float_as_uint(f);
    unsigned uh = u & 0xFFFF0000u;
    hi = (ushort)(uh >> 16);
    lo = f2bf(f - __uint_as_float(uh));
}

// ---------------- dtype detection ----------------
__global__ __launch_bounds__(256) void k_detect(const ushort* __restrict__ w1, int* __restrict__ flags) {
    __shared__ int sm[256];
    int t = threadIdx.x;
    int cnt = 0;
    for (int i = t; i < 32768; i += 256) {
        int e = (w1[i] >> 7) & 0xFF;
        if (e >= 0xC8) cnt++;
    }
    sm[t] = cnt; __syncthreads();
    for (int off = 128; off > 0; off >>= 1) {
        if (t < off) sm[t] += sm[t + off];
        __syncthreads();
    }
    if (t == 0) { flags[0] = (sm[0] > 0) ? 1 : 0; flags[1] = 1; }
}

// ---------------- CSR build: ONE atomic pass, 4 edges/thread ----------------
__global__ __launch_bounds__(256) void k_count(const int4* __restrict__ dst4, int* __restrict__ deg,
                                               int4* __restrict__ pos4) {
    int i = blockIdx.x * 256 + threadIdx.x;
    if (i < N_EDGES / 4) {
        int4 d = dst4[i];
        int4 p;
        p.x = atomicAdd(&deg[d.x], 1);
        p.y = atomicAdd(&deg[d.y], 1);
        p.z = atomicAdd(&deg[d.z], 1);
        p.w = atomicAdd(&deg[d.w], 1);
        pos4[i] = p;
    }
}

__global__ __launch_bounds__(256) void k_scan1(const int* __restrict__ deg, int* __restrict__ tmp, int* __restrict__ bsum) {
    __shared__ int sm[256];
    int t = threadIdx.x;
    int i = blockIdx.x * 256 + t;
    int x = (i < N_NODES) ? deg[i] : 0;
    sm[t] = x; __syncthreads();
    for (int off = 1; off < 256; off <<= 1) {
        int v = (t >= off) ? sm[t - off] : 0;
        __syncthreads();
        sm[t] += v;
        __syncthreads();
    }
    if (i < N_NODES) tmp[i] = sm[t];
    if (t == 255) bsum[blockIdx.x] = sm[255];
}

__global__ __launch_bounds__(256) void k_scan2(const int* __restrict__ bsum, int* __restrict__ boff) {
    __shared__ int sm[256];
    int t = threadIdx.x;
    int x = (t < SCAN_BLKS) ? bsum[t] : 0;
    sm[t] = x; __syncthreads();
    for (int off = 1; off < 256; off <<= 1) {
        int v = (t >= off) ? sm[t - off] : 0;
        __syncthreads();
        sm[t] += v;
        __syncthreads();
    }
    boff[t] = sm[t] - x;   // exclusive
}

__global__ __launch_bounds__(256) void k_scan3(const int* __restrict__ tmp, const int* __restrict__ boff, int* __restrict__ rowptr) {
    int i = blockIdx.x * 256 + threadIdx.x;
    if (i < N_NODES) rowptr[i + 1] = tmp[i] + boff[i >> 8];
    if (i == 0) rowptr[0] = 0;
}

// place pass: NO atomics, 4 edges/thread
__global__ __launch_bounds__(256) void k_place(const int4* __restrict__ src4, const int4* __restrict__ dst4,
                                               const int* __restrict__ rowptr, const int4* __restrict__ pos4,
                                               int* __restrict__ esrc) {
    int i = blockIdx.x * 256 + threadIdx.x;
    if (i < N_EDGES / 4) {
        int4 s = src4[i], d = dst4[i], p = pos4[i];
        esrc[rowptr[d.x] + p.x] = s.x;
        esrc[rowptr[d.y] + p.y] = s.y;
        esrc[rowptr[d.z] + p.z] = s.z;
        esrc[rowptr[d.w] + p.w] = s.w;
    }
}

// ---- extended weight prep: Bt[144][K] (bf16 hi/lo), transposed.
// rows 0..127 = W columns; 128..135 = W@al (el fold); 136..143 = W@ar.
__global__ __launch_bounds__(256) void k_wprep(const void* __restrict__ W, const void* __restrict__ al,
                                               const void* __restrict__ ar, int K, int kshift,
                                               ushort* __restrict__ whi, ushort* __restrict__ wlo,
                                               const int* __restrict__ flags) {
    int isf32 = flags[0];
    int idx = blockIdx.x * 256 + threadIdx.x;
    if (idx >= 144 * K) return;
    int n = idx >> kshift, k = idx & (K - 1);
    float f;
    if (n < 128) {
        f = ldf(W, (size_t)k * 128 + n, isf32);
    } else if (n < 136) {
        int h = n - 128;
        f = 0.f;
#pragma unroll
        for (int d = 0; d < HDIM; ++d)
            f = fmaf(ldf(W, (size_t)k * 128 + h * 16 + d, isf32), ldf(al, h * 16 + d, isf32), f);
    } else {
        int h = n - 136;
        f = 0.f;
#pragma unroll
        for (int d = 0; d < HDIM; ++d)
            f = fmaf(ldf(W, (size_t)k * 128 + h * 16 + d, isf32), ldf(ar, h * 16 + d, isf32), f);
    }
    ushort hi = f2bf(f);
    wlo[n * K + k] = f2bf(f - bf2f(hi));
    whi[n * K + k] = hi;
}

// ---------------- bias convert (both layers in one launch) ----------------
__global__ __launch_bounds__(256) void k_cvt2(const void* __restrict__ b1, const void* __restrict__ b2,
                                              float* __restrict__ o1, float* __restrict__ o2,
                                              const int* __restrict__ flags) {
    int isf32 = flags[0];
    int i = threadIdx.x;
    if (i < 128) o1[i] = ldf(b1, i, isf32);
    else o2[i - 128] = ldf(b2, i - 128, isf32);
}

// ---------------- GEMM layer 1: one wave per (row-tile, c-tile) ----------------
// grid (782, 9); block = 4 waves = 4 consecutive row-tiles, same c (B L1-reuse).
// K=256. A split to bf16 hi/lo in-loop (fp32 path) or direct (bf16 path).
__global__ __launch_bounds__(256) void k_gemm1(const void* __restrict__ A,
                                               const ushort* __restrict__ Bhi, const ushort* __restrict__ Blo,
                                               _Float16* __restrict__ featg,
                                               float* __restrict__ el, float* __restrict__ er,
                                               const int* __restrict__ flags) {
    int isf32 = flags[0];
    int wave = threadIdx.x >> 6;
    int lane = threadIdx.x & 63;
    int rt = blockIdx.x * 4 + wave;
    if (rt >= RTILES) return;
    int c = blockIdx.y;
    int quad = lane >> 4, l16 = lane & 15;
    const int K = 256;
    size_t a_off = (size_t)(rt * 16 + l16) * K + quad * 8;
    const ushort* bh = Bhi + (size_t)(c * 16 + l16) * K + quad * 8;
    const ushort* bl = Blo + (size_t)(c * 16 + l16) * K + quad * 8;
    f32x4 acc = {0.f, 0.f, 0.f, 0.f};
#pragma unroll 2
    for (int kk = 0; kk < K; kk += 32) {
        short8 bhi8 = *(const short8*)(bh + kk);
        short8 blo8 = *(const short8*)(bl + kk);
        if (isf32) {
            const float* ap = (const float*)A + a_off + kk;
            f32x4 u0 = *(const f32x4*)(ap);
            f32x4 u1 = *(const f32x4*)(ap + 4);
            float a8[8] = {u0[0], u0[1], u0[2], u0[3], u1[0], u1[1], u1[2], u1[3]};
            short8 ahi, alo;
#pragma unroll
            for (int j = 0; j < 8; ++j) {
                ushort h, l;
                splitbf(a8[j], h, l);
                ahi[j] = (short)h; alo[j] = (short)l;
            }
            acc = __builtin_amdgcn_mfma_f32_16x16x32_bf16(ahi, bhi8, acc, 0, 0, 0);
            acc = __builtin_amdgcn_mfma_f32_16x16x32_bf16(ahi, blo8, acc, 0, 0, 0);
            acc = __builtin_amdgcn_mfma_f32_16x16x32_bf16(alo, bhi8, acc, 0, 0, 0);
        } else {
            short8 ahi = *(const short8*)((const ushort*)A + a_off + kk);
            acc = __builtin_amdgcn_mfma_f32_16x16x32_bf16(ahi, bhi8, acc, 0, 0, 0);
            acc = __builtin_amdgcn_mfma_f32_16x16x32_bf16(ahi, blo8, acc, 0, 0, 0);
        }
    }
    // C/D layout: col = lane&15, row = (lane>>4)*4 + reg
    int rowb = rt * 16 + quad * 4;
    if (c < 8) {
#pragma unroll
        for (int r = 0; r < 4; ++r)
            featg[(size_t)(rowb + r) * D1 + c * 16 + l16] = (_Float16)acc[r];
    } else {
#pragma unroll
        for (int r = 0; r < 4; ++r) {
            int row = rowb + r;
            if (l16 < 8) el[row * 8 + l16] = acc[r];
            else         er[row * 8 + (l16 - 8)] = acc[r];
        }
    }
}

// ---------------- GEMM layer 2: A pre-split (a2hi/a2lo bf16), K=128 ----------------
__global__ __launch_bounds__(256) void k_gemm2(const ushort* __restrict__ a2hi, const ushort* __restrict__ a2lo,
                                               const ushort* __restrict__ Bhi, const ushort* __restrict__ Blo,
                                               _Float16* __restrict__ featg,
                                               float* __restrict__ el, float* __restrict__ er) {
    int wave = threadIdx.x >> 6;
    int lane = threadIdx.x & 63;
    int rt = blockIdx.x * 4 + wave;
    if (rt >= RTILES) return;
    int c = blockIdx.y;
    int quad = lane >> 4, l16 = lane & 15;
    const int K = 128;
    size_t a_off = (size_t)(rt * 16 + l16) * K + quad * 8;
    const ushort* bh = Bhi + (size_t)(c * 16 + l16) * K + quad * 8;
    const ushort* bl = Blo + (size_t)(c * 16 + l16) * K + quad * 8;
    f32x4 acc = {0.f, 0.f, 0.f, 0.f};
#pragma unroll 2
    for (int kk = 0; kk < K; kk += 32) {
        short8 ahi = *(const short8*)(a2hi + a_off + kk);
        short8 alo = *(const short8*)(a2lo + a_off + kk);
        short8 bhi8 = *(const short8*)(bh + kk);
        short8 blo8 = *(const short8*)(bl + kk);
        acc = __builtin_amdgcn_mfma_f32_16x16x32_bf16(ahi, bhi8, acc, 0, 0, 0);
        acc = __builtin_amdgcn_mfma_f32_16x16x32_bf16(ahi, blo8, acc, 0, 0, 0);
        acc = __builtin_amdgcn_mfma_f32_16x16x32_bf16(alo, bhi8, acc, 0, 0, 0);
    }
    int rowb = rt * 16 + quad * 4;
    if (c < 8) {
#pragma unroll
        for (int r = 0; r < 4; ++r)
            featg[(size_t)(rowb + r) * D1 + c * 16 + l16] = (_Float16)acc[r];
    } else {
#pragma unroll
        for (int r = 0; r < 4; ++r) {
            int row = rowb + r;
            if (l16 < 8) el[row * 8 + l16] = acc[r];
            else         er[row * 8 + (l16 - 8)] = acc[r];
        }
    }
}

// ---------------- aggregate: one wave per dst node, batch-8 edges ----------------
// mode 0: h = elu(agg+bias), stored as SPLIT bf16 hi/lo (packed 2/lane) for gemm2
// mode 1: head-mean -> d_out (bf16 or fp32 per flag)
__global__ __launch_bounds__(256) void k_agg(const int* __restrict__ rowptr, const int* __restrict__ esrc,
                                             const half2v* __restrict__ featg,
                                             const float* __restrict__ el, const float* __restrict__ er,
                                             const float* __restrict__ bias,
                                             void* __restrict__ out, unsigned* __restrict__ olo,
                                             int mode, const int* __restrict__ flags) {
    int wv = threadIdx.x >> 6;
    int lane = threadIdx.x & 63;
    int v = blockIdx.x * 4 + wv;
    if (v >= N_NODES) return;
    int h8 = lane & 7;            // logit head for this lane
    int esel = lane >> 3;         // logit edge-in-batch; also consumer head
    float erv = er[v * 8 + h8];
    int beg = rowptr[v], end = rowptr[v + 1];
    int deg = end - beg;
    float acc0 = 0.f, acc1 = 0.f, den = 0.f;
    int jend = beg + (deg & ~7);
    for (int j = beg; j < jend; j += 8) {
        int sv = esrc[j + h8];               // lane L: src of edge j+(L&7)
        int se = __shfl(sv, esel);
        float x = el[se * 8 + h8] + erv;     // logit(edge j+esel, head h8)
        x = x > 0.f ? x : NEG_SLOPE * x;
        float w = __expf(x);                 // lane e*8+m: weight(edge j+e, head m)
        int s_[8];
#pragma unroll
        for (int e = 0; e < 8; ++e) s_[e] = __shfl(sv, e);
        half2v hh_[8];
#pragma unroll
        for (int e = 0; e < 8; ++e) hh_[e] = featg[(size_t)s_[e] * 64 + lane];
        float we_[8];
#pragma unroll
        for (int e = 0; e < 8; ++e) we_[e] = __shfl(w, e * 8 + esel);
#pragma unroll
        for (int e = 0; e < 8; ++e) {
            den += we_[e];
            acc0 = fmaf(we_[e], (float)hh_[e][0], acc0);
            acc1 = fmaf(we_[e], (float)hh_[e][1], acc1);
        }
    }
    int rem = deg & 7;
    if (rem) {
        int idx = jend + h8;
        if (idx >= end) idx = end - 1;       // clamp (rem>0 -> end-1 >= jend)
        int sv = esrc[idx];
        int se = __shfl(sv, esel);
        float x = el[se * 8 + h8] + erv;
        x = x > 0.f ? x : NEG_SLOPE * x;
        float w = __expf(x);
        for (int e = 0; e < rem; ++e) {      // wave-uniform trip count
            float we = __shfl(w, e * 8 + esel);
            int s = __shfl(sv, e);
            half2v hh = featg[(size_t)s * 64 + lane];
            den += we;
            acc0 = fmaf(we, (float)hh[0], acc0);
            acc1 = fmaf(we, (float)hh[1], acc1);
        }
    }
    float inv = (deg > 0) ? 1.0f / den : 0.f;
    float2 bb = ((const float2*)bias)[lane];
    float r0 = fmaf(acc0, inv, bb.x);
    float r1 = fmaf(acc1, inv, bb.y);
    if (mode == 0) {
        r0 = r0 > 0.f ? r0 : (__expf(r0) - 1.f);   // ELU
        r1 = r1 > 0.f ? r1 : (__expf(r1) - 1.f);
        ushort h0, l0, h1, l1;
        splitbf(r0, h0, l0);
        splitbf(r1, h1, l1);
        ((unsigned*)out)[(size_t)v * 64 + lane] = (unsigned)h0 | ((unsigned)h1 << 16);
        olo[(size_t)v * 64 + lane] = (unsigned)l0 | ((unsigned)l1 << 16);
    } else {
        // mean over heads: lanes i, i^8, i^16, i^32 hold same channels of different heads
        for (int m = 8; m < 64; m <<= 1) {
            r0 += __shfl_xor(r0, m);
            r1 += __shfl_xor(r1, m);
        }
        if (lane < 8) {
            float v0 = r0 * 0.125f, v1 = r1 * 0.125f;
            if (flags[0]) {
                float2 st = {v0, v1};
                ((float2*)out)[(size_t)v * 8 + lane] = st;
            } else {
                unsigned pk = (unsigned)f2bf(v0) | ((unsigned)f2bf(v1) << 16);
                ((unsigned*)out)[(size_t)v * 8 + lane] = pk;
            }
        }
    }
}

// ---------------- workspace layout (bytes) ----------------
#define O_ROWPTR   0              // 200064
#define O_DEG      200064         // 200064
#define O_BSUM     400128         // 4096
#define O_BOFF     404224         // 4096
#define O_TMPSCAN  408320         // 200064
#define O_FLAGS    608384         // 256
#define O_POS      608640         // 6,400,000
#define O_ESRC     7008640        // 6,400,000
#define O_W1HI     13408640       // 147456 (144 x 256 bf16)
#define O_W1LO     13556096       // 147456
#define O_W2HI     13703552       // 73728  (144 x 128 bf16)
#define O_W2LO     13777280       // 73728
#define O_B1F      13851008       // 512
#define O_B2F      13851520       // 512
#define O_FEATG    13852032       // 12,800,000 (fp16 [N][128], reused by both layers)
#define O_EL       26652032       // 1,600,000
#define O_ER       28252032       // 1,600,000
#define O_A2HI     29852032       // 12,800,000 (bf16 hi of layer-1 h)
#define O_A2LO     42652032       // 12,800,000 (bf16 lo of layer-1 h)
// total ~55.5 MB (unchanged)

extern "C" void kernel_launch(void* const* d_in, const int* in_sizes, int n_in,
                              void* d_out, int out_size, void* d_ws, size_t ws_size,
                              hipStream_t stream) {
    const void* node_feat = d_in[0];
    const int* src = (const int*)d_in[1];
    const int* dst = (const int*)d_in[2];
    const void* W1 = d_in[3];
    const void* al1 = d_in[4];
    const void* ar1 = d_in[5];
    const void* b1 = d_in[6];
    const void* W2 = d_in[7];
    const void* al2 = d_in[8];
    const void* ar2 = d_in[9];
    const void* b2 = d_in[10];

    char* ws = (char*)d_ws;
    int* rowptr = (int*)(ws + O_ROWPTR);
    int* deg    = (int*)(ws + O_DEG);
    int* bsum   = (int*)(ws + O_BSUM);
    int* boff   = (int*)(ws + O_BOFF);
    int* tmpsc  = (int*)(ws + O_TMPSCAN);
    int* flags  = (int*)(ws + O_FLAGS);
    int* pos    = (int*)(ws + O_POS);
    int* esrc   = (int*)(ws + O_ESRC);
    ushort* w1hi = (ushort*)(ws + O_W1HI);
    ushort* w1lo = (ushort*)(ws + O_W1LO);
    ushort* w2hi = (ushort*)(ws + O_W2HI);
    ushort* w2lo = (ushort*)(ws + O_W2LO);
    float* b1f  = (float*)(ws + O_B1F);
    float* b2f  = (float*)(ws + O_B2F);
    _Float16* featg = (_Float16*)(ws + O_FEATG);
    float* el   = (float*)(ws + O_EL);
    float* er   = (float*)(ws + O_ER);
    ushort* a2hi = (ushort*)(ws + O_A2HI);
    ushort* a2lo = (ushort*)(ws + O_A2LO);

    const int EB4 = (N_EDGES / 4 + 255) / 256;  // 1563
    const dim3 GG((RTILES + 3) / 4, 9);         // gemm grid: 782 x 9

    // dtype detection (must precede every flag reader)
    k_detect<<<1, 256, 0, stream>>>((const ushort*)W1, flags);

    // CSR build: one atomic pass + scan + atomic-free place
    hipMemsetAsync(ws + O_DEG, 0, N_NODES * 4, stream);
    k_count<<<EB4, 256, 0, stream>>>((const int4*)dst, deg, (int4*)pos);
    k_scan1<<<SCAN_BLKS, 256, 0, stream>>>(deg, tmpsc, bsum);
    k_scan2<<<1, 256, 0, stream>>>(bsum, boff);
    k_scan3<<<SCAN_BLKS, 256, 0, stream>>>(tmpsc, boff, rowptr);
    k_place<<<EB4, 256, 0, stream>>>((const int4*)src, (const int4*)dst, rowptr, (const int4*)pos, esrc);

    // weight prep (al/ar folded in) + bias converts
    k_wprep<<<(144 * 256 + 255) / 256, 256, 0, stream>>>(W1, al1, ar1, 256, 8, w1hi, w1lo, flags);
    k_wprep<<<(144 * 128 + 255) / 256, 256, 0, stream>>>(W2, al2, ar2, 128, 7, w2hi, w2lo, flags);
    k_cvt2<<<1, 256, 0, stream>>>(b1, b2, b1f, b2f, flags);

    // layer 1
    k_gemm1<<<GG, 256, 0, stream>>>(node_feat, w1hi, w1lo, featg, el, er, flags);
    k_agg<<<(N_NODES + 3) / 4, 256, 0, stream>>>(rowptr, esrc, (const half2v*)featg, el, er, b1f,
                                                 (void*)a2hi, (unsigned*)a2lo, 0, flags);

    // layer 2
    k_gemm2<<<GG, 256, 0, stream>>>(a2hi, a2lo, w2hi, w2lo, featg, el, er);
    k_agg<<<(N_NODES + 3) / 4, 256, 0, stream>>>(rowptr, esrc, (const half2v*)featg, el, er, b2f,
                                                 (void*)d_out, nullptr, 1, flags);
}

// Round 7
// 469.920 us; speedup vs baseline: 1.0920x; 1.0920x over previous
//
#include <hip/hip_runtime.h>
#include <hip/hip_bf16.h>

#define N_NODES 50000
#define N_EDGES 1600000
#define HEADS 8
#define HDIM 16
#define D1 128   // HEADS*HDIM
#define NEG_SLOPE 0.2f
#define SCAN_BLKS 196  // ceil(50000/256)
#define RTILES 3125    // 50000/16

typedef short short8 __attribute__((ext_vector_type(8)));
typedef float f32x4 __attribute__((ext_vector_type(4)));
typedef _Float16 half2v __attribute__((ext_vector_type(2)));

// ---- dtype helpers (flag: 1 = buffers are fp32, 0 = bf16) ----
__device__ __forceinline__ float bf2f(ushort u) {
    union { unsigned u; float f; } x; x.u = ((unsigned)u) << 16; return x.f;
}
__device__ __forceinline__ ushort f2bf(float f) {
    union { float f; unsigned u; } x; x.f = f;
    unsigned r = x.u + 0x7FFF + ((x.u >> 16) & 1);   // RNE
    return (ushort)(r >> 16);
}
__device__ __forceinline__ float ldf(const void* p, size_t i, int isf32) {
    return isf32 ? ((const float*)p)[i] : bf2f(((const ushort*)p)[i]);
}
// split f into hi (truncated bf16) + lo (RNE bf16 of residual): ~2^-17 rel combined
__device__ __forceinline__ void splitbf(float f, ushort& hi, ushort& lo) {
    unsigned u = __float_as_uint(f);
    unsigned uh = u & 0xFFFF0000u;
    hi = (ushort)(uh >> 16);
    lo = f2bf(f - __uint_as_float(uh));
}

// ---------------- dtype detection ----------------
__global__ __launch_bounds__(256) void k_detect(const ushort* __restrict__ w1, int* __restrict__ flags) {
    __shared__ int sm[256];
    int t = threadIdx.x;
    int cnt = 0;
    for (int i = t; i < 32768; i += 256) {
        int e = (w1[i] >> 7) & 0xFF;
        if (e >= 0xC8) cnt++;
    }
    sm[t] = cnt; __syncthreads();
    for (int off = 128; off > 0; off >>= 1) {
        if (t < off) sm[t] += sm[t + off];
        __syncthreads();
    }
    if (t == 0) { flags[0] = (sm[0] > 0) ? 1 : 0; flags[1] = 1; }
}

// ---------------- CSR build: ONE atomic pass, 4 edges/thread ----------------
__global__ __launch_bounds__(256) void k_count(const int4* __restrict__ dst4, int* __restrict__ deg,
                                               int4* __restrict__ pos4) {
    int i = blockIdx.x * 256 + threadIdx.x;
    if (i < N_EDGES / 4) {
        int4 d = dst4[i];
        int4 p;
        p.x = atomicAdd(&deg[d.x], 1);
        p.y = atomicAdd(&deg[d.y], 1);
        p.z = atomicAdd(&deg[d.z], 1);
        p.w = atomicAdd(&deg[d.w], 1);
        pos4[i] = p;
    }
}

__global__ __launch_bounds__(256) void k_scan1(const int* __restrict__ deg, int* __restrict__ tmp, int* __restrict__ bsum) {
    __shared__ int sm[256];
    int t = threadIdx.x;
    int i = blockIdx.x * 256 + t;
    int x = (i < N_NODES) ? deg[i] : 0;
    sm[t] = x; __syncthreads();
    for (int off = 1; off < 256; off <<= 1) {
        int v = (t >= off) ? sm[t - off] : 0;
        __syncthreads();
        sm[t] += v;
        __syncthreads();
    }
    if (i < N_NODES) tmp[i] = sm[t];
    if (t == 255) bsum[blockIdx.x] = sm[255];
}

__global__ __launch_bounds__(256) void k_scan2(const int* __restrict__ bsum, int* __restrict__ boff) {
    __shared__ int sm[256];
    int t = threadIdx.x;
    int x = (t < SCAN_BLKS) ? bsum[t] : 0;
    sm[t] = x; __syncthreads();
    for (int off = 1; off < 256; off <<= 1) {
        int v = (t >= off) ? sm[t - off] : 0;
        __syncthreads();
        sm[t] += v;
        __syncthreads();
    }
    boff[t] = sm[t] - x;   // exclusive
}

__global__ __launch_bounds__(256) void k_scan3(const int* __restrict__ tmp, const int* __restrict__ boff, int* __restrict__ rowptr) {
    int i = blockIdx.x * 256 + threadIdx.x;
    if (i < N_NODES) rowptr[i + 1] = tmp[i] + boff[i >> 8];
    if (i == 0) rowptr[0] = 0;
}

// place pass: NO atomics, 4 edges/thread
__global__ __launch_bounds__(256) void k_place(const int4* __restrict__ src4, const int4* __restrict__ dst4,
                                               const int* __restrict__ rowptr, const int4* __restrict__ pos4,
                                               int* __restrict__ esrc) {
    int i = blockIdx.x * 256 + threadIdx.x;
    if (i < N_EDGES / 4) {
        int4 s = src4[i], d = dst4[i], p = pos4[i];
        esrc[rowptr[d.x] + p.x] = s.x;
        esrc[rowptr[d.y] + p.y] = s.y;
        esrc[rowptr[d.z] + p.z] = s.z;
        esrc[rowptr[d.w] + p.w] = s.w;
    }
}

// ---- extended weight prep: Bt[144][K] (bf16 hi/lo), transposed.
// rows 0..127 = W columns; 128..135 = W@al (el fold); 136..143 = W@ar.
// NOTE: bf16 input path -> rows 0..127 of lo are exactly 0 (exploited in gemm).
__global__ __launch_bounds__(256) void k_wprep(const void* __restrict__ W, const void* __restrict__ al,
                                               const void* __restrict__ ar, int K, int kshift,
                                               ushort* __restrict__ whi, ushort* __restrict__ wlo,
                                               const int* __restrict__ flags) {
    int isf32 = flags[0];
    int idx = blockIdx.x * 256 + threadIdx.x;
    if (idx >= 144 * K) return;
    int n = idx >> kshift, k = idx & (K - 1);
    float f;
    if (n < 128) {
        f = ldf(W, (size_t)k * 128 + n, isf32);
    } else if (n < 136) {
        int h = n - 128;
        f = 0.f;
#pragma unroll
        for (int d = 0; d < HDIM; ++d)
            f = fmaf(ldf(W, (size_t)k * 128 + h * 16 + d, isf32), ldf(al, h * 16 + d, isf32), f);
    } else {
        int h = n - 136;
        f = 0.f;
#pragma unroll
        for (int d = 0; d < HDIM; ++d)
            f = fmaf(ldf(W, (size_t)k * 128 + h * 16 + d, isf32), ldf(ar, h * 16 + d, isf32), f);
    }
    ushort hi = f2bf(f);
    wlo[n * K + k] = f2bf(f - bf2f(hi));
    whi[n * K + k] = hi;
}

// ---------------- bias convert (both layers in one launch) ----------------
__global__ __launch_bounds__(256) void k_cvt2(const void* __restrict__ b1, const void* __restrict__ b2,
                                              float* __restrict__ o1, float* __restrict__ o2,
                                              const int* __restrict__ flags) {
    int isf32 = flags[0];
    int i = threadIdx.x;
    if (i < 128) o1[i] = ldf(b1, i, isf32);
    else o2[i - 128] = ldf(b2, i - 128, isf32);
}

// ---------------- GEMM layer 1 ----------------
// grid (782, 2). Wave = one 16-row A panel held ENTIRELY in registers
// (8 back-to-back loads -> deep MLP). y=0: c 0..3, y=1: c 4..7 + el/er tile c=8.
// bf16-A path: 1 MFMA per main c-tile (Blo==0 there); fp32 path: 3.
__global__ __launch_bounds__(256) void k_gemm1(const void* __restrict__ A,
                                               const ushort* __restrict__ Bhi, const ushort* __restrict__ Blo,
                                               _Float16* __restrict__ featg,
                                               float* __restrict__ el, float* __restrict__ er,
                                               const int* __restrict__ flags) {
    int isf32 = flags[0];
    int wave = threadIdx.x >> 6;
    int lane = threadIdx.x & 63;
    int rt = blockIdx.x * 4 + wave;
    if (rt >= RTILES) return;
    int cbase = blockIdx.y * 4;
    int quad = lane >> 4, l16 = lane & 15;
    const int K = 256;
    size_t a_off = (size_t)(rt * 16 + l16) * K + quad * 8;
    int rowb = rt * 16 + quad * 4;

    short8 ahi[8], alo[8];
    if (isf32) {
        const float* ap = (const float*)A + a_off;
#pragma unroll
        for (int i = 0; i < 8; ++i) {
            f32x4 u0 = *(const f32x4*)(ap + 32 * i);
            f32x4 u1 = *(const f32x4*)(ap + 32 * i + 4);
            float a8[8] = {u0[0], u0[1], u0[2], u0[3], u1[0], u1[1], u1[2], u1[3]};
#pragma unroll
            for (int j = 0; j < 8; ++j) {
                ushort h, l;
                splitbf(a8[j], h, l);
                ahi[i][j] = (short)h; alo[i][j] = (short)l;
            }
        }
    } else {
        const ushort* ap = (const ushort*)A + a_off;
#pragma unroll
        for (int i = 0; i < 8; ++i) ahi[i] = *(const short8*)(ap + 32 * i);
    }

#pragma unroll
    for (int ci = 0; ci < 4; ++ci) {
        int c = cbase + ci;
        const ushort* bh = Bhi + (size_t)(c * 16 + l16) * K + quad * 8;
        f32x4 acc = {0.f, 0.f, 0.f, 0.f};
        if (isf32) {
            const ushort* bl = Blo + (size_t)(c * 16 + l16) * K + quad * 8;
#pragma unroll
            for (int k = 0; k < 8; ++k) {
                short8 bh8 = *(const short8*)(bh + 32 * k);
                short8 bl8 = *(const short8*)(bl + 32 * k);
                acc = __builtin_amdgcn_mfma_f32_16x16x32_bf16(ahi[k], bh8, acc, 0, 0, 0);
                acc = __builtin_amdgcn_mfma_f32_16x16x32_bf16(ahi[k], bl8, acc, 0, 0, 0);
                acc = __builtin_amdgcn_mfma_f32_16x16x32_bf16(alo[k], bh8, acc, 0, 0, 0);
            }
        } else {
#pragma unroll
            for (int k = 0; k < 8; ++k) {
                short8 bh8 = *(const short8*)(bh + 32 * k);
                acc = __builtin_amdgcn_mfma_f32_16x16x32_bf16(ahi[k], bh8, acc, 0, 0, 0);
            }
        }
#pragma unroll
        for (int r = 0; r < 4; ++r)
            featg[(size_t)(rowb + r) * D1 + c * 16 + l16] = (_Float16)acc[r];
    }

    if (cbase == 4) {   // el/er fold tile (c=8): B lo always needed
        const ushort* bh = Bhi + (size_t)(8 * 16 + l16) * K + quad * 8;
        const ushort* bl = Blo + (size_t)(8 * 16 + l16) * K + quad * 8;
        f32x4 acc = {0.f, 0.f, 0.f, 0.f};
#pragma unroll
        for (int k = 0; k < 8; ++k) {
            short8 bh8 = *(const short8*)(bh + 32 * k);
            short8 bl8 = *(const short8*)(bl + 32 * k);
            acc = __builtin_amdgcn_mfma_f32_16x16x32_bf16(ahi[k], bh8, acc, 0, 0, 0);
            acc = __builtin_amdgcn_mfma_f32_16x16x32_bf16(ahi[k], bl8, acc, 0, 0, 0);
            if (isf32) acc = __builtin_amdgcn_mfma_f32_16x16x32_bf16(alo[k], bh8, acc, 0, 0, 0);
        }
#pragma unroll
        for (int r = 0; r < 4; ++r) {
            int row = rowb + r;
            if (l16 < 8) el[row * 8 + l16] = acc[r];
            else         er[row * 8 + (l16 - 8)] = acc[r];
        }
    }
}

// ---------------- GEMM layer 2: A pre-split (a2hi/a2lo bf16), K=128 ----------------
__global__ __launch_bounds__(256) void k_gemm2(const ushort* __restrict__ a2hi, const ushort* __restrict__ a2lo,
                                               const ushort* __restrict__ Bhi, const ushort* __restrict__ Blo,
                                               _Float16* __restrict__ featg,
                                               float* __restrict__ el, float* __restrict__ er,
                                               const int* __restrict__ flags) {
    int isf32 = flags[0];
    int wave = threadIdx.x >> 6;
    int lane = threadIdx.x & 63;
    int rt = blockIdx.x * 4 + wave;
    if (rt >= RTILES) return;
    int cbase = blockIdx.y * 4;
    int quad = lane >> 4, l16 = lane & 15;
    const int K = 128;
    size_t a_off = (size_t)(rt * 16 + l16) * K + quad * 8;
    int rowb = rt * 16 + quad * 4;

    short8 ahi[4], alo[4];
#pragma unroll
    for (int i = 0; i < 4; ++i) ahi[i] = *(const short8*)(a2hi + a_off + 32 * i);
#pragma unroll
    for (int i = 0; i < 4; ++i) alo[i] = *(const short8*)(a2lo + a_off + 32 * i);

#pragma unroll
    for (int ci = 0; ci < 4; ++ci) {
        int c = cbase + ci;
        const ushort* bh = Bhi + (size_t)(c * 16 + l16) * K + quad * 8;
        const ushort* bl = Blo + (size_t)(c * 16 + l16) * K + quad * 8;
        f32x4 acc = {0.f, 0.f, 0.f, 0.f};
#pragma unroll
        for (int k = 0; k < 4; ++k) {
            short8 bh8 = *(const short8*)(bh + 32 * k);
            acc = __builtin_amdgcn_mfma_f32_16x16x32_bf16(ahi[k], bh8, acc, 0, 0, 0);
            acc = __builtin_amdgcn_mfma_f32_16x16x32_bf16(alo[k], bh8, acc, 0, 0, 0);
            if (isf32) {
                short8 bl8 = *(const short8*)(bl + 32 * k);
                acc = __builtin_amdgcn_mfma_f32_16x16x32_bf16(ahi[k], bl8, acc, 0, 0, 0);
            }
        }
#pragma unroll
        for (int r = 0; r < 4; ++r)
            featg[(size_t)(rowb + r) * D1 + c * 16 + l16] = (_Float16)acc[r];
    }

    if (cbase == 4) {   // el/er fold tile (c=8)
        const ushort* bh = Bhi + (size_t)(8 * 16 + l16) * K + quad * 8;
        const ushort* bl = Blo + (size_t)(8 * 16 + l16) * K + quad * 8;
        f32x4 acc = {0.f, 0.f, 0.f, 0.f};
#pragma unroll
        for (int k = 0; k < 4; ++k) {
            short8 bh8 = *(const short8*)(bh + 32 * k);
            short8 bl8 = *(const short8*)(bl + 32 * k);
            acc = __builtin_amdgcn_mfma_f32_16x16x32_bf16(ahi[k], bh8, acc, 0, 0, 0);
            acc = __builtin_amdgcn_mfma_f32_16x16x32_bf16(ahi[k], bl8, acc, 0, 0, 0);
            acc = __builtin_amdgcn_mfma_f32_16x16x32_bf16(alo[k], bh8, acc, 0, 0, 0);
        }
#pragma unroll
        for (int r = 0; r < 4; ++r) {
            int row = rowb + r;
            if (l16 < 8) el[row * 8 + l16] = acc[r];
            else         er[row * 8 + (l16 - 8)] = acc[r];
        }
    }
}

// ---------------- aggregate: one wave per dst node, batch-8 edges ----------------
// mode 0: h = elu(agg+bias), stored as SPLIT bf16 hi/lo (packed 2/lane) for gemm2
// mode 1: head-mean -> d_out (bf16 or fp32 per flag)
__global__ __launch_bounds__(256) void k_agg(const int* __restrict__ rowptr, const int* __restrict__ esrc,
                                             const half2v* __restrict__ featg,
                                             const float* __restrict__ el, const float* __restrict__ er,
                                             const float* __restrict__ bias,
                                             void* __restrict__ out, unsigned* __restrict__ olo,
                                             int mode, const int* __restrict__ flags) {
    int wv = threadIdx.x >> 6;
    int lane = threadIdx.x & 63;
    int v = blockIdx.x * 4 + wv;
    if (v >= N_NODES) return;
    int h8 = lane & 7;            // logit head for this lane
    int esel = lane >> 3;         // logit edge-in-batch; also consumer head
    float erv = er[v * 8 + h8];
    int beg = rowptr[v], end = rowptr[v + 1];
    int deg = end - beg;
    float acc0 = 0.f, acc1 = 0.f, den = 0.f;
    int jend = beg + (deg & ~7);
    for (int j = beg; j < jend; j += 8) {
        int sv = esrc[j + h8];               // lane L: src of edge j+(L&7)
        int se = __shfl(sv, esel);
        float x = el[se * 8 + h8] + erv;     // logit(edge j+esel, head h8)
        x = x > 0.f ? x : NEG_SLOPE * x;
        float w = __expf(x);                 // lane e*8+m: weight(edge j+e, head m)
        int s_[8];
#pragma unroll
        for (int e = 0; e < 8; ++e) s_[e] = __shfl(sv, e);
        half2v hh_[8];
#pragma unroll
        for (int e = 0; e < 8; ++e) hh_[e] = featg[(size_t)s_[e] * 64 + lane];
        float we_[8];
#pragma unroll
        for (int e = 0; e < 8; ++e) we_[e] = __shfl(w, e * 8 + esel);
#pragma unroll
        for (int e = 0; e < 8; ++e) {
            den += we_[e];
            acc0 = fmaf(we_[e], (float)hh_[e][0], acc0);
            acc1 = fmaf(we_[e], (float)hh_[e][1], acc1);
        }
    }
    int rem = deg & 7;
    if (rem) {
        int idx = jend + h8;
        if (idx >= end) idx = end - 1;       // clamp (rem>0 -> end-1 >= jend)
        int sv = esrc[idx];
        int se = __shfl(sv, esel);
        float x = el[se * 8 + h8] + erv;
        x = x > 0.f ? x : NEG_SLOPE * x;
        float w = __expf(x);
        for (int e = 0; e < rem; ++e) {      // wave-uniform trip count
            float we = __shfl(w, e * 8 + esel);
            int s = __shfl(sv, e);
            half2v hh = featg[(size_t)s * 64 + lane];
            den += we;
            acc0 = fmaf(we, (float)hh[0], acc0);
            acc1 = fmaf(we, (float)hh[1], acc1);
        }
    }
    float inv = (deg > 0) ? 1.0f / den : 0.f;
    float2 bb = ((const float2*)bias)[lane];
    float r0 = fmaf(acc0, inv, bb.x);
    float r1 = fmaf(acc1, inv, bb.y);
    if (mode == 0) {
        r0 = r0 > 0.f ? r0 : (__expf(r0) - 1.f);   // ELU
        r1 = r1 > 0.f ? r1 : (__expf(r1) - 1.f);
        ushort h0, l0, h1, l1;
        splitbf(r0, h0, l0);
        splitbf(r1, h1, l1);
        ((unsigned*)out)[(size_t)v * 64 + lane] = (unsigned)h0 | ((unsigned)h1 << 16);
        olo[(size_t)v * 64 + lane] = (unsigned)l0 | ((unsigned)l1 << 16);
    } else {
        // mean over heads: lanes i, i^8, i^16, i^32 hold same channels of different heads
        for (int m = 8; m < 64; m <<= 1) {
            r0 += __shfl_xor(r0, m);
            r1 += __shfl_xor(r1, m);
        }
        if (lane < 8) {
            float v0 = r0 * 0.125f, v1 = r1 * 0.125f;
            if (flags[0]) {
                float2 st = {v0, v1};
                ((float2*)out)[(size_t)v * 8 + lane] = st;
            } else {
                unsigned pk = (unsigned)f2bf(v0) | ((unsigned)f2bf(v1) << 16);
                ((unsigned*)out)[(size_t)v * 8 + lane] = pk;
            }
        }
    }
}

// ---------------- workspace layout (bytes) ----------------
#define O_ROWPTR   0              // 200064
#define O_DEG      200064         // 200064
#define O_BSUM     400128         // 4096
#define O_BOFF     404224         // 4096
#define O_TMPSCAN  408320         // 200064
#define O_FLAGS    608384         // 256
#define O_POS      608640         // 6,400,000
#define O_ESRC     7008640        // 6,400,000
#define O_W1HI     13408640       // 147456 (144 x 256 bf16)
#define O_W1LO     13556096       // 147456
#define O_W2HI     13703552       // 73728  (144 x 128 bf16)
#define O_W2LO     13777280       // 73728
#define O_B1F      13851008       // 512
#define O_B2F      13851520       // 512
#define O_FEATG    13852032       // 12,800,000 (fp16 [N][128], reused by both layers)
#define O_EL       26652032       // 1,600,000
#define O_ER       28252032       // 1,600,000
#define O_A2HI     29852032       // 12,800,000 (bf16 hi of layer-1 h)
#define O_A2LO     42652032       // 12,800,000 (bf16 lo of layer-1 h)
// total ~55.5 MB

extern "C" void kernel_launch(void* const* d_in, const int* in_sizes, int n_in,
                              void* d_out, int out_size, void* d_ws, size_t ws_size,
                              hipStream_t stream) {
    const void* node_feat = d_in[0];
    const int* src = (const int*)d_in[1];
    const int* dst = (const int*)d_in[2];
    const void* W1 = d_in[3];
    const void* al1 = d_in[4];
    const void* ar1 = d_in[5];
    const void* b1 = d_in[6];
    const void* W2 = d_in[7];
    const void* al2 = d_in[8];
    const void* ar2 = d_in[9];
    const void* b2 = d_in[10];

    char* ws = (char*)d_ws;
    int* rowptr = (int*)(ws + O_ROWPTR);
    int* deg    = (int*)(ws + O_DEG);
    int* bsum   = (int*)(ws + O_BSUM);
    int* boff   = (int*)(ws + O_BOFF);
    int* tmpsc  = (int*)(ws + O_TMPSCAN);
    int* flags  = (int*)(ws + O_FLAGS);
    int* pos    = (int*)(ws + O_POS);
    int* esrc   = (int*)(ws + O_ESRC);
    ushort* w1hi = (ushort*)(ws + O_W1HI);
    ushort* w1lo = (ushort*)(ws + O_W1LO);
    ushort* w2hi = (ushort*)(ws + O_W2HI);
    ushort* w2lo = (ushort*)(ws + O_W2LO);
    float* b1f  = (float*)(ws + O_B1F);
    float* b2f  = (float*)(ws + O_B2F);
    _Float16* featg = (_Float16*)(ws + O_FEATG);
    float* el   = (float*)(ws + O_EL);
    float* er   = (float*)(ws + O_ER);
    ushort* a2hi = (ushort*)(ws + O_A2HI);
    ushort* a2lo = (ushort*)(ws + O_A2LO);

    const int EB4 = (N_EDGES / 4 + 255) / 256;  // 1563
    const dim3 GG((RTILES + 3) / 4, 2);         // gemm grid: 782 x 2 c-groups

    // dtype detection (must precede every flag reader)
    k_detect<<<1, 256, 0, stream>>>((const ushort*)W1, flags);

    // CSR build: one atomic pass + scan + atomic-free place
    hipMemsetAsync(ws + O_DEG, 0, N_NODES * 4, stream);
    k_count<<<EB4, 256, 0, stream>>>((const int4*)dst, deg, (int4*)pos);
    k_scan1<<<SCAN_BLKS, 256, 0, stream>>>(deg, tmpsc, bsum);
    k_scan2<<<1, 256, 0, stream>>>(bsum, boff);
    k_scan3<<<SCAN_BLKS, 256, 0, stream>>>(tmpsc, boff, rowptr);
    k_place<<<EB4, 256, 0, stream>>>((const int4*)src, (const int4*)dst, rowptr, (const int4*)pos, esrc);

    // weight prep (al/ar folded in) + bias converts
    k_wprep<<<(144 * 256 + 255) / 256, 256, 0, stream>>>(W1, al1, ar1, 256, 8, w1hi, w1lo, flags);
    k_wprep<<<(144 * 128 + 255) / 256, 256, 0, stream>>>(W2, al2, ar2, 128, 7, w2hi, w2lo, flags);
    k_cvt2<<<1, 256, 0, stream>>>(b1, b2, b1f, b2f, flags);

    // layer 1
    k_gemm1<<<GG, 256, 0, stream>>>(node_feat, w1hi, w1lo, featg, el, er, flags);
    k_agg<<<(N_NODES + 3) / 4, 256, 0, stream>>>(rowptr, esrc, (const half2v*)featg, el, er, b1f,
                                                 (void*)a2hi, (unsigned*)a2lo, 0, flags);

    // layer 2
    k_gemm2<<<GG, 256, 0, stream>>>(a2hi, a2lo, w2hi, w2lo, featg, el, er, flags);
    k_agg<<<(N_NODES + 3) / 4, 256, 0, stream>>>(rowptr, esrc, (const half2v*)featg, el, er, b2f,
                                                 (void*)d_out, nullptr, 1, flags);
}

// Round 8
// 461.544 us; speedup vs baseline: 1.1118x; 1.0181x over previous
//
#include <hip/hip_runtime.h>
#include <hip/hip_bf16.h>

#define N_NODES 50000
#define N_EDGES 1600000
#define HEADS 8
#define HDIM 16
#define D1 128   // HEADS*HDIM
#define NEG_SLOPE 0.2f
#define SCAN_BLKS 196  // ceil(50000/256)
#define RTILES 3125    // 50000/16

typedef short short8 __attribute__((ext_vector_type(8)));
typedef float f32x4 __attribute__((ext_vector_type(4)));
typedef _Float16 half2v __attribute__((ext_vector_type(2)));

// ---- dtype helpers (flag: 1 = buffers are fp32, 0 = bf16) ----
__device__ __forceinline__ float bf2f(ushort u) {
    union { unsigned u; float f; } x; x.u = ((unsigned)u) << 16; return x.f;
}
__device__ __forceinline__ ushort f2bf(float f) {
    union { float f; unsigned u; } x; x.f = f;
    unsigned r = x.u + 0x7FFF + ((x.u >> 16) & 1);   // RNE
    return (ushort)(r >> 16);
}
__device__ __forceinline__ float ldf(const void* p, size_t i, int isf32) {
    return isf32 ? ((const float*)p)[i] : bf2f(((const ushort*)p)[i]);
}
// split f into hi (truncated bf16) + lo (RNE bf16 of residual): ~2^-17 rel combined
__device__ __forceinline__ void splitbf(float f, ushort& hi, ushort& lo) {
    unsigned u = __float_as_uint(f);
    unsigned uh = u & 0xFFFF0000u;
    hi = (ushort)(uh >> 16);
    lo = f2bf(f - __uint_as_float(uh));
}

// ---------------- dtype detection ----------------
__global__ __launch_bounds__(256) void k_detect(const ushort* __restrict__ w1, int* __restrict__ flags) {
    __shared__ int sm[256];
    int t = threadIdx.x;
    int cnt = 0;
    for (int i = t; i < 32768; i += 256) {
        int e = (w1[i] >> 7) & 0xFF;
        if (e >= 0xC8) cnt++;
    }
    sm[t] = cnt; __syncthreads();
    for (int off = 128; off > 0; off >>= 1) {
        if (t < off) sm[t] += sm[t + off];
        __syncthreads();
    }
    if (t == 0) { flags[0] = (sm[0] > 0) ? 1 : 0; flags[1] = 1; }
}

// ---------------- CSR build: ONE atomic pass, 4 edges/thread ----------------
__global__ __launch_bounds__(256) void k_count(const int4* __restrict__ dst4, int* __restrict__ deg,
                                               int4* __restrict__ pos4) {
    int i = blockIdx.x * 256 + threadIdx.x;
    if (i < N_EDGES / 4) {
        int4 d = dst4[i];
        int4 p;
        p.x = atomicAdd(&deg[d.x], 1);
        p.y = atomicAdd(&deg[d.y], 1);
        p.z = atomicAdd(&deg[d.z], 1);
        p.w = atomicAdd(&deg[d.w], 1);
        pos4[i] = p;
    }
}

__global__ __launch_bounds__(256) void k_scan1(const int* __restrict__ deg, int* __restrict__ tmp, int* __restrict__ bsum) {
    __shared__ int sm[256];
    int t = threadIdx.x;
    int i = blockIdx.x * 256 + t;
    int x = (i < N_NODES) ? deg[i] : 0;
    sm[t] = x; __syncthreads();
    for (int off = 1; off < 256; off <<= 1) {
        int v = (t >= off) ? sm[t - off] : 0;
        __syncthreads();
        sm[t] += v;
        __syncthreads();
    }
    if (i < N_NODES) tmp[i] = sm[t];
    if (t == 255) bsum[blockIdx.x] = sm[255];
}

// scan2 folded into scan3: every block redundantly scans the 196 block sums.
__global__ __launch_bounds__(256) void k_scan23(const int* __restrict__ tmp, const int* __restrict__ bsum,
                                                int* __restrict__ rowptr) {
    __shared__ int sm[256];
    int t = threadIdx.x;
    int x = (t < SCAN_BLKS) ? bsum[t] : 0;
    sm[t] = x; __syncthreads();
    for (int off = 1; off < 256; off <<= 1) {
        int v = (t >= off) ? sm[t - off] : 0;
        __syncthreads();
        sm[t] += v;
        __syncthreads();
    }
    int boff = sm[blockIdx.x] - ((blockIdx.x < SCAN_BLKS) ? bsum[blockIdx.x] : 0);  // exclusive prefix
    int i = blockIdx.x * 256 + t;
    if (i < N_NODES) rowptr[i + 1] = tmp[i] + boff;
    if (i == 0) rowptr[0] = 0;
}

// place pass: NO atomics, 4 edges/thread
__global__ __launch_bounds__(256) void k_place(const int4* __restrict__ src4, const int4* __restrict__ dst4,
                                               const int* __restrict__ rowptr, const int4* __restrict__ pos4,
                                               int* __restrict__ esrc) {
    int i = blockIdx.x * 256 + threadIdx.x;
    if (i < N_EDGES / 4) {
        int4 s = src4[i], d = dst4[i], p = pos4[i];
        esrc[rowptr[d.x] + p.x] = s.x;
        esrc[rowptr[d.y] + p.y] = s.y;
        esrc[rowptr[d.z] + p.z] = s.z;
        esrc[rowptr[d.w] + p.w] = s.w;
    }
}

// ---- fused prep: wprep(W1) [blocks 0..143] + wprep(W2) [144..215] + bias cvt [216].
// Bt[144][K] (bf16 hi/lo), transposed. rows 0..127 = W cols; 128..135 = W@al; 136..143 = W@ar.
// bf16 input path -> rows 0..127 of lo are exactly 0 (exploited in gemm).
__device__ __forceinline__ void wprep_body(const void* W, const void* al, const void* ar,
                                           int K, int kshift, ushort* whi, ushort* wlo,
                                           int isf32, int idx) {
    if (idx >= 144 * K) return;
    int n = idx >> kshift, k = idx & (K - 1);
    float f;
    if (n < 128) {
        f = ldf(W, (size_t)k * 128 + n, isf32);
    } else if (n < 136) {
        int h = n - 128;
        f = 0.f;
#pragma unroll
        for (int d = 0; d < HDIM; ++d)
            f = fmaf(ldf(W, (size_t)k * 128 + h * 16 + d, isf32), ldf(al, h * 16 + d, isf32), f);
    } else {
        int h = n - 136;
        f = 0.f;
#pragma unroll
        for (int d = 0; d < HDIM; ++d)
            f = fmaf(ldf(W, (size_t)k * 128 + h * 16 + d, isf32), ldf(ar, h * 16 + d, isf32), f);
    }
    ushort hi = f2bf(f);
    wlo[n * K + k] = f2bf(f - bf2f(hi));
    whi[n * K + k] = hi;
}

__global__ __launch_bounds__(256) void k_prep(const void* __restrict__ W1, const void* __restrict__ al1,
                                              const void* __restrict__ ar1, const void* __restrict__ b1,
                                              const void* __restrict__ W2, const void* __restrict__ al2,
                                              const void* __restrict__ ar2, const void* __restrict__ b2,
                                              ushort* __restrict__ w1hi, ushort* __restrict__ w1lo,
                                              ushort* __restrict__ w2hi, ushort* __restrict__ w2lo,
                                              float* __restrict__ b1f, float* __restrict__ b2f,
                                              const int* __restrict__ flags) {
    int isf32 = flags[0];
    int b = blockIdx.x;
    if (b < 144) {
        wprep_body(W1, al1, ar1, 256, 8, w1hi, w1lo, isf32, b * 256 + threadIdx.x);
    } else if (b < 216) {
        wprep_body(W2, al2, ar2, 128, 7, w2hi, w2lo, isf32, (b - 144) * 256 + threadIdx.x);
    } else {
        int i = threadIdx.x;
        if (i < 128) b1f[i] = ldf(b1, i, isf32);
        else b2f[i - 128] = ldf(b2, i - 128, isf32);
    }
}

// ---- coalesced featg tile store: wave's 16x64 fp16 tile via LDS (72-elem padded rows) ----
__device__ __forceinline__ void store_tile(_Float16 (*sfe)[72], _Float16* __restrict__ featg,
                                           const f32x4* acc, int lane, int quad, int l16,
                                           int rowb0, int cbase) {
#pragma unroll
    for (int ci = 0; ci < 4; ++ci)
#pragma unroll
        for (int r = 0; r < 4; ++r)
            sfe[quad * 4 + r][ci * 16 + l16] = (_Float16)acc[ci][r];
    // no __syncthreads: same-wave producer/consumer (compiler inserts lgkmcnt)
    int rr = lane >> 3, ch = lane & 7;
#pragma unroll
    for (int s = 0; s < 2; ++s) {
        int row = s * 8 + rr;
        short8 v = *(const short8*)&sfe[row][ch * 8];
        *(short8*)(featg + (size_t)(rowb0 + row) * D1 + cbase * 16 + ch * 8) = v;
    }
}

// ---------------- GEMM layer 1 ----------------
// grid (782, 2). Wave = one 16-row A panel in registers. y=0: c 0..3, y=1: c 4..7 + el/er (c=8).
__global__ __launch_bounds__(256) void k_gemm1(const void* __restrict__ A,
                                               const ushort* __restrict__ Bhi, const ushort* __restrict__ Blo,
                                               _Float16* __restrict__ featg,
                                               float* __restrict__ el, float* __restrict__ er,
                                               const int* __restrict__ flags) {
    __shared__ _Float16 sfe[4][16][72];
    int isf32 = flags[0];
    int wave = threadIdx.x >> 6;
    int lane = threadIdx.x & 63;
    int rt = blockIdx.x * 4 + wave;
    if (rt >= RTILES) return;
    int cbase = blockIdx.y * 4;
    int quad = lane >> 4, l16 = lane & 15;
    const int K = 256;
    size_t a_off = (size_t)(rt * 16 + l16) * K + quad * 8;
    int rowb0 = rt * 16;

    short8 ahi[8], alo[8];
    if (isf32) {
        const float* ap = (const float*)A + a_off;
#pragma unroll
        for (int i = 0; i < 8; ++i) {
            f32x4 u0 = *(const f32x4*)(ap + 32 * i);
            f32x4 u1 = *(const f32x4*)(ap + 32 * i + 4);
            float a8[8] = {u0[0], u0[1], u0[2], u0[3], u1[0], u1[1], u1[2], u1[3]};
#pragma unroll
            for (int j = 0; j < 8; ++j) {
                ushort h, l;
                splitbf(a8[j], h, l);
                ahi[i][j] = (short)h; alo[i][j] = (short)l;
            }
        }
    } else {
        const ushort* ap = (const ushort*)A + a_off;
#pragma unroll
        for (int i = 0; i < 8; ++i) ahi[i] = *(const short8*)(ap + 32 * i);
    }

    f32x4 acc[4];
#pragma unroll
    for (int ci = 0; ci < 4; ++ci) acc[ci] = (f32x4){0.f, 0.f, 0.f, 0.f};
#pragma unroll
    for (int ci = 0; ci < 4; ++ci) {
        int c = cbase + ci;
        const ushort* bh = Bhi + (size_t)(c * 16 + l16) * K + quad * 8;
        if (isf32) {
            const ushort* bl = Blo + (size_t)(c * 16 + l16) * K + quad * 8;
#pragma unroll
            for (int k = 0; k < 8; ++k) {
                short8 bh8 = *(const short8*)(bh + 32 * k);
                short8 bl8 = *(const short8*)(bl + 32 * k);
                acc[ci] = __builtin_amdgcn_mfma_f32_16x16x32_bf16(ahi[k], bh8, acc[ci], 0, 0, 0);
                acc[ci] = __builtin_amdgcn_mfma_f32_16x16x32_bf16(ahi[k], bl8, acc[ci], 0, 0, 0);
                acc[ci] = __builtin_amdgcn_mfma_f32_16x16x32_bf16(alo[k], bh8, acc[ci], 0, 0, 0);
            }
        } else {
#pragma unroll
            for (int k = 0; k < 8; ++k) {
                short8 bh8 = *(const short8*)(bh + 32 * k);
                acc[ci] = __builtin_amdgcn_mfma_f32_16x16x32_bf16(ahi[k], bh8, acc[ci], 0, 0, 0);
            }
        }
    }
    store_tile(sfe[wave], featg, acc, lane, quad, l16, rowb0, cbase);

    if (cbase == 4) {   // el/er fold tile (c=8): B lo always needed
        const ushort* bh = Bhi + (size_t)(8 * 16 + l16) * K + quad * 8;
        const ushort* bl = Blo + (size_t)(8 * 16 + l16) * K + quad * 8;
        f32x4 a = {0.f, 0.f, 0.f, 0.f};
#pragma unroll
        for (int k = 0; k < 8; ++k) {
            short8 bh8 = *(const short8*)(bh + 32 * k);
            short8 bl8 = *(const short8*)(bl + 32 * k);
            a = __builtin_amdgcn_mfma_f32_16x16x32_bf16(ahi[k], bh8, a, 0, 0, 0);
            a = __builtin_amdgcn_mfma_f32_16x16x32_bf16(ahi[k], bl8, a, 0, 0, 0);
            if (isf32) a = __builtin_amdgcn_mfma_f32_16x16x32_bf16(alo[k], bh8, a, 0, 0, 0);
        }
#pragma unroll
        for (int r = 0; r < 4; ++r) {
            int row = rowb0 + quad * 4 + r;
            if (l16 < 8) el[row * 8 + l16] = a[r];
            else         er[row * 8 + (l16 - 8)] = a[r];
        }
    }
}

// ---------------- GEMM layer 2: A pre-split (a2hi/a2lo bf16), K=128 ----------------
__global__ __launch_bounds__(256) void k_gemm2(const ushort* __restrict__ a2hi, const ushort* __restrict__ a2lo,
                                               const ushort* __restrict__ Bhi, const ushort* __restrict__ Blo,
                                               _Float16* __restrict__ featg,
                                               float* __restrict__ el, float* __restrict__ er,
                                               const int* __restrict__ flags) {
    __shared__ _Float16 sfe[4][16][72];
    int isf32 = flags[0];
    int wave = threadIdx.x >> 6;
    int lane = threadIdx.x & 63;
    int rt = blockIdx.x * 4 + wave;
    if (rt >= RTILES) return;
    int cbase = blockIdx.y * 4;
    int quad = lane >> 4, l16 = lane & 15;
    const int K = 128;
    size_t a_off = (size_t)(rt * 16 + l16) * K + quad * 8;
    int rowb0 = rt * 16;

    short8 ahi[4], alo[4];
#pragma unroll
    for (int i = 0; i < 4; ++i) ahi[i] = *(const short8*)(a2hi + a_off + 32 * i);
#pragma unroll
    for (int i = 0; i < 4; ++i) alo[i] = *(const short8*)(a2lo + a_off + 32 * i);

    f32x4 acc[4];
#pragma unroll
    for (int ci = 0; ci < 4; ++ci) acc[ci] = (f32x4){0.f, 0.f, 0.f, 0.f};
#pragma unroll
    for (int ci = 0; ci < 4; ++ci) {
        int c = cbase + ci;
        const ushort* bh = Bhi + (size_t)(c * 16 + l16) * K + quad * 8;
        const ushort* bl = Blo + (size_t)(c * 16 + l16) * K + quad * 8;
#pragma unroll
        for (int k = 0; k < 4; ++k) {
            short8 bh8 = *(const short8*)(bh + 32 * k);
            acc[ci] = __builtin_amdgcn_mfma_f32_16x16x32_bf16(ahi[k], bh8, acc[ci], 0, 0, 0);
            acc[ci] = __builtin_amdgcn_mfma_f32_16x16x32_bf16(alo[k], bh8, acc[ci], 0, 0, 0);
            if (isf32) {
                short8 bl8 = *(const short8*)(bl + 32 * k);
                acc[ci] = __builtin_amdgcn_mfma_f32_16x16x32_bf16(ahi[k], bl8, acc[ci], 0, 0, 0);
            }
        }
    }
    store_tile(sfe[wave], featg, acc, lane, quad, l16, rowb0, cbase);

    if (cbase == 4) {   // el/er fold tile (c=8)
        const ushort* bh = Bhi + (size_t)(8 * 16 + l16) * K + quad * 8;
        const ushort* bl = Blo + (size_t)(8 * 16 + l16) * K + quad * 8;
        f32x4 a = {0.f, 0.f, 0.f, 0.f};
#pragma unroll
        for (int k = 0; k < 4; ++k) {
            short8 bh8 = *(const short8*)(bh + 32 * k);
            short8 bl8 = *(const short8*)(bl + 32 * k);
            a = __builtin_amdgcn_mfma_f32_16x16x32_bf16(ahi[k], bh8, a, 0, 0, 0);
            a = __builtin_amdgcn_mfma_f32_16x16x32_bf16(ahi[k], bl8, a, 0, 0, 0);
            a = __builtin_amdgcn_mfma_f32_16x16x32_bf16(alo[k], bh8, a, 0, 0, 0);
        }
#pragma unroll
        for (int r = 0; r < 4; ++r) {
            int row = rowb0 + quad * 4 + r;
            if (l16 < 8) el[row * 8 + l16] = a[r];
            else         er[row * 8 + (l16 - 8)] = a[r];
        }
    }
}

// ---------------- aggregate: one wave per dst node, batch-8 edges ----------------
// mode 0: h = elu(agg+bias), stored as SPLIT bf16 hi/lo (packed 2/lane) for gemm2
// mode 1: head-mean -> d_out (bf16 or fp32 per flag)
__global__ __launch_bounds__(256) void k_agg(const int* __restrict__ rowptr, const int* __restrict__ esrc,
                                             const half2v* __restrict__ featg,
                                             const float* __restrict__ el, const float* __restrict__ er,
                                             const float* __restrict__ bias,
                                             void* __restrict__ out, unsigned* __restrict__ olo,
                                             int mode, const int* __restrict__ flags) {
    int wv = threadIdx.x >> 6;
    int lane = threadIdx.x & 63;
    int v = blockIdx.x * 4 + wv;
    if (v >= N_NODES) return;
    int h8 = lane & 7;            // logit head for this lane
    int esel = lane >> 3;         // logit edge-in-batch; also consumer head
    float erv = er[v * 8 + h8];
    int beg = rowptr[v], end = rowptr[v + 1];
    int deg = end - beg;
    float acc0 = 0.f, acc1 = 0.f, den = 0.f;
    int jend = beg + (deg & ~7);
    for (int j = beg; j < jend; j += 8) {
        int sv = esrc[j + h8];               // lane L: src of edge j+(L&7)
        int se = __shfl(sv, esel);
        float x = el[se * 8 + h8] + erv;     // logit(edge j+esel, head h8)
        x = x > 0.f ? x : NEG_SLOPE * x;
        float w = __expf(x);                 // lane e*8+m: weight(edge j+e, head m)
        int s_[8];
#pragma unroll
        for (int e = 0; e < 8; ++e) s_[e] = __shfl(sv, e);
        half2v hh_[8];
#pragma unroll
        for (int e = 0; e < 8; ++e) hh_[e] = featg[(size_t)s_[e] * 64 + lane];
        float we_[8];
#pragma unroll
        for (int e = 0; e < 8; ++e) we_[e] = __shfl(w, e * 8 + esel);
#pragma unroll
        for (int e = 0; e < 8; ++e) {
            den += we_[e];
            acc0 = fmaf(we_[e], (float)hh_[e][0], acc0);
            acc1 = fmaf(we_[e], (float)hh_[e][1], acc1);
        }
    }
    int rem = deg & 7;
    if (rem) {
        int idx = jend + h8;
        if (idx >= end) idx = end - 1;       // clamp (rem>0 -> end-1 >= jend)
        int sv = esrc[idx];
        int se = __shfl(sv, esel);
        float x = el[se * 8 + h8] + erv;
        x = x > 0.f ? x : NEG_SLOPE * x;
        float w = __expf(x);
        for (int e = 0; e < rem; ++e) {      // wave-uniform trip count
            float we = __shfl(w, e * 8 + esel);
            int s = __shfl(sv, e);
            half2v hh = featg[(size_t)s * 64 + lane];
            den += we;
            acc0 = fmaf(we, (float)hh[0], acc0);
            acc1 = fmaf(we, (float)hh[1], acc1);
        }
    }
    float inv = (deg > 0) ? 1.0f / den : 0.f;
    float2 bb = ((const float2*)bias)[lane];
    float r0 = fmaf(acc0, inv, bb.x);
    float r1 = fmaf(acc1, inv, bb.y);
    if (mode == 0) {
        r0 = r0 > 0.f ? r0 : (__expf(r0) - 1.f);   // ELU
        r1 = r1 > 0.f ? r1 : (__expf(r1) - 1.f);
        ushort h0, l0, h1, l1;
        splitbf(r0, h0, l0);
        splitbf(r1, h1, l1);
        ((unsigned*)out)[(size_t)v * 64 + lane] = (unsigned)h0 | ((unsigned)h1 << 16);
        olo[(size_t)v * 64 + lane] = (unsigned)l0 | ((unsigned)l1 << 16);
    } else {
        // mean over heads: lanes i, i^8, i^16, i^32 hold same channels of different heads
        for (int m = 8; m < 64; m <<= 1) {
            r0 += __shfl_xor(r0, m);
            r1 += __shfl_xor(r1, m);
        }
        if (lane < 8) {
            float v0 = r0 * 0.125f, v1 = r1 * 0.125f;
            if (flags[0]) {
                float2 st = {v0, v1};
                ((float2*)out)[(size_t)v * 8 + lane] = st;
            } else {
                unsigned pk = (unsigned)f2bf(v0) | ((unsigned)f2bf(v1) << 16);
                ((unsigned*)out)[(size_t)v * 8 + lane] = pk;
            }
        }
    }
}

// ---------------- workspace layout (bytes) ----------------
#define O_ROWPTR   0              // 200064
#define O_DEG      200064         // 200064
#define O_BSUM     400128         // 4096
#define O_BOFF     404224         // 4096
#define O_TMPSCAN  408320         // 200064
#define O_FLAGS    608384         // 256
#define O_POS      608640         // 6,400,000
#define O_ESRC     7008640        // 6,400,000
#define O_W1HI     13408640       // 147456 (144 x 256 bf16)
#define O_W1LO     13556096       // 147456
#define O_W2HI     13703552       // 73728  (144 x 128 bf16)
#define O_W2LO     13777280       // 73728
#define O_B1F      13851008       // 512
#define O_B2F      13851520       // 512
#define O_FEATG    13852032       // 12,800,000 (fp16 [N][128], reused by both layers)
#define O_EL       26652032       // 1,600,000
#define O_ER       28252032       // 1,600,000
#define O_A2HI     29852032       // 12,800,000 (bf16 hi of layer-1 h)
#define O_A2LO     42652032       // 12,800,000 (bf16 lo of layer-1 h)
// total ~55.5 MB

extern "C" void kernel_launch(void* const* d_in, const int* in_sizes, int n_in,
                              void* d_out, int out_size, void* d_ws, size_t ws_size,
                              hipStream_t stream) {
    const void* node_feat = d_in[0];
    const int* src = (const int*)d_in[1];
    const int* dst = (const int*)d_in[2];
    const void* W1 = d_in[3];
    const void* al1 = d_in[4];
    const void* ar1 = d_in[5];
    const void* b1 = d_in[6];
    const void* W2 = d_in[7];
    const void* al2 = d_in[8];
    const void* ar2 = d_in[9];
    const void* b2 = d_in[10];

    char* ws = (char*)d_ws;
    int* rowptr = (int*)(ws + O_ROWPTR);
    int* deg    = (int*)(ws + O_DEG);
    int* bsum   = (int*)(ws + O_BSUM);
    int* tmpsc  = (int*)(ws + O_TMPSCAN);
    int* flags  = (int*)(ws + O_FLAGS);
    int* pos    = (int*)(ws + O_POS);
    int* esrc   = (int*)(ws + O_ESRC);
    ushort* w1hi = (ushort*)(ws + O_W1HI);
    ushort* w1lo = (ushort*)(ws + O_W1LO);
    ushort* w2hi = (ushort*)(ws + O_W2HI);
    ushort* w2lo = (ushort*)(ws + O_W2LO);
    float* b1f  = (float*)(ws + O_B1F);
    float* b2f  = (float*)(ws + O_B2F);
    _Float16* featg = (_Float16*)(ws + O_FEATG);
    float* el   = (float*)(ws + O_EL);
    float* er   = (float*)(ws + O_ER);
    ushort* a2hi = (ushort*)(ws + O_A2HI);
    ushort* a2lo = (ushort*)(ws + O_A2LO);

    const int EB4 = (N_EDGES / 4 + 255) / 256;  // 1563
    const dim3 GG((RTILES + 3) / 4, 2);         // gemm grid: 782 x 2 c-groups

    // dtype detection (must precede every flag reader)
    k_detect<<<1, 256, 0, stream>>>((const ushort*)W1, flags);

    // CSR build: one atomic pass + scan (2 kernels) + atomic-free place
    hipMemsetAsync(ws + O_DEG, 0, N_NODES * 4, stream);
    k_count<<<EB4, 256, 0, stream>>>((const int4*)dst, deg, (int4*)pos);
    k_scan1<<<SCAN_BLKS, 256, 0, stream>>>(deg, tmpsc, bsum);
    k_scan23<<<SCAN_BLKS, 256, 0, stream>>>(tmpsc, bsum, rowptr);
    k_place<<<EB4, 256, 0, stream>>>((const int4*)src, (const int4*)dst, rowptr, (const int4*)pos, esrc);

    // fused weight prep (al/ar folded in) + bias converts
    k_prep<<<217, 256, 0, stream>>>(W1, al1, ar1, b1, W2, al2, ar2, b2,
                                    w1hi, w1lo, w2hi, w2lo, b1f, b2f, flags);

    // layer 1
    k_gemm1<<<GG, 256, 0, stream>>>(node_feat, w1hi, w1lo, featg, el, er, flags);
    k_agg<<<(N_NODES + 3) / 4, 256, 0, stream>>>(rowptr, esrc, (const half2v*)featg, el, er, b1f,
                                                 (void*)a2hi, (unsigned*)a2lo, 0, flags);

    // layer 2
    k_gemm2<<<GG, 256, 0, stream>>>(a2hi, a2lo, w2hi, w2lo, featg, el, er, flags);
    k_agg<<<(N_NODES + 3) / 4, 256, 0, stream>>>(rowptr, esrc, (const half2v*)featg, el, er, b2f,
                                                 (void*)d_out, nullptr, 1, flags);
}